// Round 8
// baseline (221.844 us; speedup 1.0000x reference)
//
#include <hip/hip_runtime.h>
#include <hip/hip_cooperative_groups.h>
#include <hip/hip_bf16.h>
#include <math.h>

namespace cg = cooperative_groups;

// Problem constants
#define NB      65536
#define NFQ     199
#define DTC     0.05f
#define INV_NORM (1.0f/150.0f)
#define PH_SCALE 1.2566370614359172f   // 2*pi / T_PERIOD
#define KTAY    10                      // Taylor terms for expm(DT*L) action
#define KTAY_U  18                      // Taylor terms for u = expm(i*theta)

typedef _Float16 f16x8 __attribute__((ext_vector_type(8)));
typedef _Float16 f16x2 __attribute__((ext_vector_type(2)));
typedef float    f32x4 __attribute__((ext_vector_type(4)));

static __device__ __forceinline__ f16x2 u2h(unsigned u) {
    return __builtin_bit_cast(f16x2, u);
}
static __device__ __forceinline__ unsigned packh(float lo, float hi) {
    f16x2 h; h.x = (_Float16)lo; h.y = (_Float16)hi;
    return __builtin_bit_cast(unsigned, h);
}
static __device__ __forceinline__ f16x2 cvt_pk(float lo, float hi) {
    return __builtin_bit_cast(f16x2, __builtin_amdgcn_cvt_pkrtz(lo, hi));
}
// acc += cs . w  (f16 pair dot, f32 accumulate)
static __device__ __forceinline__ float dot2(f16x2 cs, unsigned wbits, float acc) {
#if __has_builtin(__builtin_amdgcn_fdot2)
    return __builtin_amdgcn_fdot2(cs, u2h(wbits), acc, false);
#else
    f16x2 w = u2h(wbits);
    return acc + (float)cs.x * (float)w.x + (float)cs.y * (float)w.y;
#endif
}

extern __shared__ float sm[];   // dynamic LDS

// ===========================================================================
// COOPERATIVE single-kernel path. Grid 256 x 256 (1 block/CU guaranteed).
// Phase 1: blocks 0..15 basis (inline u), blocks 16..255 coef (strided chunks)
// grid.sync()
// Phase 2: all 256 blocks: MFMA L-build + Taylor action, 256 samples each.
// ===========================================================================
__global__ __launch_bounds__(256) void k_all(
        const float* __restrict__ t,   const float* __restrict__ x,
        const float* __restrict__ u_re,const float* __restrict__ u_im,
        const float* __restrict__ ag,  const float* __restrict__ wg,
        const float* __restrict__ bg,  const float* __restrict__ ao,
        const float* __restrict__ wo,  const float* __restrict__ bo,
        const float* __restrict__ f,   const float* __restrict__ dten,
        _Float16* __restrict__ Lb16,   unsigned* __restrict__ coef16,
        float* __restrict__ out) {
    int tid = threadIdx.x;
    int bid = blockIdx.x;

    if (bid < 16) {
        // ================= basis path =================
        if (bid == 15) {   // zero slices g=15, g=31
            int c = tid >> 4, r = tid & 15;
            Lb16[c*512 + r*32 + 15] = (_Float16)0.0f;
            Lb16[c*512 + r*32 + 31] = (_Float16)0.0f;
        } else {
            int p = bid;
            unsigned* fd16 = (unsigned*)sm;     // 3600 uints: (f,d) f16 pairs, [a][b][k] stride16
            float* S    = sm + 3600;            // 3600: FR+DI merged, [n][j][k] stride16
            float* Rm   = sm + 7200;            // 225
            float* Im   = sm + 7425;            // 225
            float* accA = sm + 7650;            // 225
            float* colv = sm + 7875;            // 15
            float* sur  = sm + 7890;            // 15
            float* sui  = sm + 7905;            // 15
            // u-compute scratch overlays the S region (done before S is written)
            float* Mre  = sm + 3600;            // 225
            float* Mim  = sm + 3825;            // 225
            float* creb = sm + 4050;            // 2 x 225
            float* cimb = sm + 4500;            // 2 x 225

            for (int idx = tid; idx < 3600; idx += 256) {
                int k = idx & 15, ab = idx >> 4;
                float fv = 0.0f, dv = 0.0f;
                if (k < 15) { fv = f[ab*15 + k]; dv = dten[ab*15 + k]; }
                fd16[idx] = packh(fv, dv);
            }
            // ---- u = expm(i*theta), skew-Hermitian Taylor (redundant/block) ----
            float accre = 0.0f, accim = 0.0f;
            if (tid < 225) {
                int a = tid / 15, b = tid % 15;
                float tre = u_re[a*15+b] + u_re[b*15+a];
                float tim = u_im[a*15+b] - u_im[b*15+a];
                Mre[tid] = -tim;
                Mim[tid] =  tre;
                float id = (a == b) ? 1.0f : 0.0f;
                creb[tid] = id; cimb[tid] = 0.0f;
                accre = id;
            }
            __syncthreads();
            int cur = 0;
            for (int k = 1; k <= KTAY_U; ++k) {
                float nre = 0.0f, nim = 0.0f;
                if (tid < 225) {
                    int a = tid / 15, b = tid % 15;
                    for (int j = 0; j < 15; ++j) {
                        float mre = Mre[a*15+j], mim = Mim[a*15+j];
                        float xre = creb[cur*225 + j*15+b], xim = cimb[cur*225 + j*15+b];
                        nre += mre*xre - mim*xim;
                        nim += mre*xim + mim*xre;
                    }
                    float inv = 1.0f / (float)k;
                    nre *= inv; nim *= inv;
                    creb[(cur^1)*225 + tid] = nre; cimb[(cur^1)*225 + tid] = nim;
                    accre += nre; accim += nim;
                }
                __syncthreads();
                cur ^= 1;
            }
            // column p of u
            if (tid < 225 && (tid % 15) == p) { sur[tid/15] = accre; sui[tid/15] = accim; }
            __syncthreads();
            if (tid < 225) {
                int i = tid / 15, j = tid % 15;
                Rm[tid] = sur[i]*sur[j] + sui[i]*sui[j];   // Re(u_ip conj(u_jp))
                Im[tid] = sui[i]*sur[j] - sur[i]*sui[j];   // Im(u_ip conj(u_jp))
            }
            __syncthreads();
            // S[n][j][k] = sum_i f[n,i,k]*Rm[i,j] + sum_i d[n,i,k]*Im[j,i]
            for (int idx = tid; idx < 3600; idx += 256) {
                int k  = idx & 15;
                int nj = idx >> 4;
                int n  = nj / 15;
                int j  = nj % 15;
                float s1 = 0.0f, s2 = 0.0f;
                if (k < 15) {
                    for (int i = 0; i < 15; ++i) {
                        f16x2 fd = u2h(fd16[(n*15+i)*16 + k]);
                        s1 += (float)fd.x * Rm[i*15 + j];
                        s2 += (float)fd.y * Im[j*15 + i];
                    }
                }
                S[idx] = s1 + s2;
            }
            __syncthreads();
            if (tid < 225) {
                int m = tid / 15, n = tid % 15;
                float acc = 0.0f;
                for (int j = 0; j < 15; ++j) {
                    const unsigned* fa = &fd16[(m*15+j)*16];
                    const float*    fs = &S   [(n*15+j)*16];
                    for (int k = 0; k < 15; ++k) {
                        f16x2 fd = u2h(fa[k]);
                        acc += (float)fd.x * fs[k];
                    }
                }
                accA[tid] = -8.0f * acc;
            }
            if (tid < 15) {
                int m = tid;
                float s = 0.0f;
                for (int i = 0; i < 15; ++i)
                    for (int j = 0; j < 15; ++j) {
                        f16x2 fd = u2h(fd16[(i*15+m)*16 + j]);
                        s += (float)fd.x * Im[i*15 + j];
                    }
                colv[m] = 4.0f * s;
            }
            __syncthreads();
            {
                int c = tid >> 4, r = tid & 15;
                float vg, vo;
                if (r == 0)      { vg = 0.0f;              vo = 0.0f; }
                else if (c == 0) { vg = colv[r-1];         vo = 0.0f; }
                else             { vg = accA[(r-1)*15 + (c-1)];
                                   f16x2 fd = u2h(fd16[(p*15 + (r-1))*16 + (c-1)]);
                                   vo = -4.0f * (float)fd.x; }
                Lb16[c*512 + r*32 + p]      = (_Float16)vg;
                Lb16[c*512 + r*32 + 16 + p] = (_Float16)vo;
            }
        }
    } else {
        // ================= coef path (blocks 16..255) =================
        unsigned* lw = (unsigned*)sm;       // 200 rows x 36 uints (28.8 KB)
        for (int idx = tid; idx < 200*36; idx += 256) lw[idx] = 0u;
        __syncthreads();
        // build f16 (cos,sin) weight table inline; lanes sweep n -> coalesced
        for (int idx = tid; idx < 15*200; idx += 256) {
            int m = idx / 200, n = idx % 200;
            if (n < NFQ)
                lw[n*36 + m] = packh(wg[m*398 + n]       * ag[n],
                                     wg[m*398 + 199 + n] * ag[199 + n]);
        }
        for (int idx = tid; idx < 15*200; idx += 256) {
            int m = idx / 200, n = idx % 200;
            if (n < NFQ)
                lw[n*36 + 16 + m] = packh(wo[m*398 + n]       * ao[n],
                                          wo[m*398 + 199 + n] * ao[199 + n]);
        }
        __syncthreads();

        int q = tid & 3;          // quad lane: freq rows 4k+q
        int pp = tid >> 2;        // 0..63

        float bgv[15], bov[15];
#pragma unroll
        for (int m = 0; m < 15; ++m) { bgv[m] = bg[m]; bov[m] = bo[m]; }

        // 256 chunks of 256 samples over 240 blocks (blocks 16..31 take 2)
        for (int cb = bid - 16; cb < 256; cb += 240) {
            int sbase = cb * 256 + pp;

            float rc[4], rs[4], rc4[4], rs4[4];
#pragma unroll
            for (int i = 0; i < 4; ++i) {
                float d = 0.5f * PH_SCALE * t[sbase + 64*i];
                __sincosf((float)(q + 1) * d, &rs[i], &rc[i]);
                __sincosf(4.0f * d, &rs4[i], &rc4[i]);
            }

            float ga[4][15], oa[4][15];
#pragma unroll
            for (int i = 0; i < 4; ++i)
#pragma unroll
                for (int m = 0; m < 15; ++m) { ga[i][m] = 0.0f; oa[i][m] = 0.0f; }

#pragma unroll 1
            for (int k = 0; k < 50; ++k) {
                const uint4* rowv = (const uint4*)(lw + (4*k + q) * 36);
                unsigned us[32];
#pragma unroll
                for (int j = 0; j < 8; ++j) {
                    uint4 a_ = rowv[j];
                    us[4*j] = a_.x; us[4*j+1] = a_.y; us[4*j+2] = a_.z; us[4*j+3] = a_.w;
                }
#pragma unroll
                for (int i = 0; i < 4; ++i) {
                    f16x2 cs = cvt_pk(rc[i], rs[i]);
#pragma unroll
                    for (int m = 0; m < 15; ++m) {
                        ga[i][m] = dot2(cs, us[m],      ga[i][m]);
                        oa[i][m] = dot2(cs, us[16 + m], oa[i][m]);
                    }
                    float cn = rc[i]*rc4[i] - rs[i]*rs4[i];
                    float sn = rs[i]*rc4[i] + rc[i]*rs4[i];
                    rc[i] = cn; rs[i] = sn;
                }
            }

#pragma unroll
            for (int i = 0; i < 4; ++i)
#pragma unroll
                for (int m = 0; m < 15; ++m) {
                    ga[i][m] += __shfl_xor(ga[i][m], 1, 64);
                    ga[i][m] += __shfl_xor(ga[i][m], 2, 64);
                    oa[i][m] += __shfl_xor(oa[i][m], 1, 64);
                    oa[i][m] += __shfl_xor(oa[i][m], 2, 64);
                }

#pragma unroll
            for (int i = 0; i < 4; ++i) {
                float rv[32];
#pragma unroll
                for (int m = 0; m < 15; ++m) {
                    float g = ga[i][m] + bgv[m];
                    rv[m]      = g * g * INV_NORM;
                    rv[16 + m] = (oa[i][m] + bov[m]) * INV_NORM;
                }
                rv[15] = 0.0f; rv[31] = 0.0f;
                unsigned u0  = packh(rv[0],  rv[1]),  u1  = packh(rv[2],  rv[3]);
                unsigned u2  = packh(rv[4],  rv[5]),  u3  = packh(rv[6],  rv[7]);
                unsigned u4  = packh(rv[8],  rv[9]),  u5  = packh(rv[10], rv[11]);
                unsigned u6  = packh(rv[12], rv[13]), u7  = packh(rv[14], rv[15]);
                unsigned u8  = packh(rv[16], rv[17]), u9  = packh(rv[18], rv[19]);
                unsigned u10 = packh(rv[20], rv[21]), u11 = packh(rv[22], rv[23]);
                unsigned u12 = packh(rv[24], rv[25]), u13 = packh(rv[26], rv[27]);
                unsigned u14 = packh(rv[28], rv[29]), u15 = packh(rv[30], rv[31]);
                uint4 wr;
                if      (q == 0) wr = make_uint4(u0,  u1,  u2,  u3);
                else if (q == 1) wr = make_uint4(u4,  u5,  u6,  u7);
                else if (q == 2) wr = make_uint4(u8,  u9,  u10, u11);
                else             wr = make_uint4(u12, u13, u14, u15);
                *(uint4*)(coef16 + (size_t)(sbase + 64*i) * 16 + 4*q) = wr;
            }
        }
    }

    __threadfence();
    cg::this_grid().sync();

    // ================= main phase: 256 blocks, 256 samples each =============
    float* wl = sm;                          // 4 waves x 16 samples x stride20
    int wave = tid >> 6, lane = tid & 63;
    int grp  = lane >> 4, sl = lane & 15;
    f32x4 zero4 = {0.0f, 0.0f, 0.0f, 0.0f};
    float* slot = wl + wave*320 + sl*20;

#pragma unroll 1
    for (int pass = 0; pass < 4; ++pass) {
        int s = (bid << 8) + (pass << 6) + (wave << 4) + sl;

        // B fragment: cf[s][k], k = grp*8 + j  (one 16B load)
        f16x8 bh = *(const f16x8*)((const _Float16*)coef16 + (size_t)s * 32 + grp * 8);

        // 16 MFMAs: acc[c].i = L[s][4*grp+i][c]
        f32x4 acc[16];
#pragma unroll
        for (int c = 0; c < 16; ++c) {
            f16x8 af = *(const f16x8*)(Lb16 + c*512 + sl*32 + grp*8);
            acc[c] = __builtin_amdgcn_mfma_f32_16x16x32_f16(af, bh, zero4, 0, 0, 0);
        }

        // w0 = [1; x] rows 4*grp..4*grp+3
        float4 wv;
        if (grp == 0) {
            const float* xp = x + (size_t)s * 15;
            wv = make_float4(1.0f, xp[0], xp[1], xp[2]);
        } else {
            const float* xp = x + (size_t)s * 15 + 4*grp - 1;
            wv = make_float4(xp[0], xp[1], xp[2], xp[3]);
        }
        float4 accv = wv;

#pragma unroll
        for (int k = 1; k <= KTAY; ++k) {
            *(float4*)(slot + 4*grp) = wv;      // wave-synchronous, in-order DS
            float wz[16];
            {
                float4 a = *(const float4*)(slot + 0);
                wz[0]=a.x; wz[1]=a.y; wz[2]=a.z; wz[3]=a.w;
                float4 b = *(const float4*)(slot + 4);
                wz[4]=b.x; wz[5]=b.y; wz[6]=b.z; wz[7]=b.w;
                float4 c = *(const float4*)(slot + 8);
                wz[8]=c.x; wz[9]=c.y; wz[10]=c.z; wz[11]=c.w;
                float4 d = *(const float4*)(slot + 12);
                wz[12]=d.x; wz[13]=d.y; wz[14]=d.z; wz[15]=d.w;
            }
            float nx = 0.0f, ny = 0.0f, nz = 0.0f, nw = 0.0f;
#pragma unroll
            for (int c = 0; c < 16; ++c) {
                f32x4 A = acc[c];
                float wc = wz[c];
                nx += A.x * wc; ny += A.y * wc; nz += A.z * wc; nw += A.w * wc;
            }
            float sc = DTC / (float)k;
            wv = make_float4(nx*sc, ny*sc, nz*sc, nw*sc);
            accv.x += wv.x; accv.y += wv.y; accv.z += wv.z; accv.w += wv.w;
        }

        float* op = out + (size_t)s * 15 - 1;
        int row = 4 * grp;
        if (row > 0) op[row] = accv.x;
        op[row + 1] = accv.y;
        op[row + 2] = accv.z;
        op[row + 3] = accv.w;
    }
}

// ===========================================================================
// FALLBACK path — proven round-6 three-kernel pipeline (used only if the
// cooperative launch is rejected by the runtime).
// ===========================================================================
__global__ __launch_bounds__(256) void k_pre(const float* __restrict__ u_re,
                                             const float* __restrict__ u_im,
                                             const float* __restrict__ ag,
                                             const float* __restrict__ wg,
                                             const float* __restrict__ ao,
                                             const float* __restrict__ wo,
                                             float* __restrict__ ws_u,
                                             unsigned* __restrict__ wt16) {
    int tid = threadIdx.x;
    if (blockIdx.x == 0) {
        __shared__ float Mre[225], Mim[225];
        __shared__ float cre[2][225], cim[2][225];
        float accre = 0.0f, accim = 0.0f;
        if (tid < 225) {
            int a = tid / 15, b = tid % 15;
            float tre = u_re[a*15+b] + u_re[b*15+a];
            float tim = u_im[a*15+b] - u_im[b*15+a];
            Mre[tid] = -tim;
            Mim[tid] =  tre;
            float id = (a == b) ? 1.0f : 0.0f;
            cre[0][tid] = id; cim[0][tid] = 0.0f;
            accre = id;
        }
        __syncthreads();
        int cur = 0;
        for (int k = 1; k <= 30; ++k) {
            float nre = 0.0f, nim = 0.0f;
            if (tid < 225) {
                int a = tid / 15, b = tid % 15;
                for (int j = 0; j < 15; ++j) {
                    float mre = Mre[a*15+j], mim = Mim[a*15+j];
                    float xre = cre[cur][j*15+b], xim = cim[cur][j*15+b];
                    nre += mre*xre - mim*xim;
                    nim += mre*xim + mim*xre;
                }
                float inv = 1.0f / (float)k;
                nre *= inv; nim *= inv;
                cre[cur^1][tid] = nre; cim[cur^1][tid] = nim;
                accre += nre; accim += nim;
            }
            __syncthreads();
            cur ^= 1;
        }
        if (tid < 225) {
            ws_u[2*tid]   = accre;
            ws_u[2*tid+1] = accim;
        }
    } else {
        int n = blockIdx.x - 1;
        if (tid < 32) {
            unsigned v = 0u;
            if (n < NFQ) {
                if (tid < 15) {
                    v = packh(wg[tid*398 + n] * ag[n],
                              wg[tid*398 + 199 + n] * ag[199 + n]);
                } else if (tid >= 16 && tid < 31) {
                    int m = tid - 16;
                    v = packh(wo[m*398 + n] * ao[n],
                              wo[m*398 + 199 + n] * ao[199 + n]);
                }
            }
            wt16[n*36 + tid] = v;
        }
    }
}

__global__ __launch_bounds__(256) void k_mid(const float* __restrict__ f,
                                             const float* __restrict__ dten,
                                             const float* __restrict__ ws_u,
                                             const float* __restrict__ t,
                                             const float* __restrict__ bg,
                                             const float* __restrict__ bo,
                                             const unsigned* __restrict__ wt16,
                                             _Float16* __restrict__ Lb16,
                                             unsigned* __restrict__ coef16) {
    int tid = threadIdx.x;
    if (blockIdx.x < 16) {
        int p = blockIdx.x;
        int c = tid >> 4, r = tid & 15;
        if (p == 15) {
            Lb16[c*512 + r*32 + 15] = (_Float16)0.0f;
            Lb16[c*512 + r*32 + 31] = (_Float16)0.0f;
            return;
        }
        float* fsp  = sm;
        float* dshp = sm + 3600;
        float* FRt  = sm + 7200;
        float* DIt  = sm + 10800;
        float* Rm   = sm + 14400;
        float* Im   = sm + 14625;
        float* accA = sm + 14850;
        float* colv = sm + 15075;
        float* sur  = sm + 15090;
        float* sui  = sm + 15105;

        for (int idx = tid; idx < 3600; idx += 256) {
            int k = idx & 15, ab = idx >> 4;
            float fv = 0.0f, dv = 0.0f;
            if (k < 15) { fv = f[ab*15 + k]; dv = dten[ab*15 + k]; }
            fsp[idx] = fv; dshp[idx] = dv;
        }
        if (tid < 15) {
            sur[tid] = ws_u[2*(tid*15 + p)];
            sui[tid] = ws_u[2*(tid*15 + p) + 1];
        }
        __syncthreads();

        if (tid < 225) {
            int i = tid / 15, j = tid % 15;
            Rm[tid] = sur[i]*sur[j] + sui[i]*sui[j];
            Im[tid] = sui[i]*sur[j] - sur[i]*sui[j];
        }
        __syncthreads();

        for (int idx = tid; idx < 3600; idx += 256) {
            int k  = idx & 15;
            int nj = idx >> 4;
            int n  = nj / 15;
            int j  = nj % 15;
            float s1 = 0.0f, s2 = 0.0f;
            if (k < 15) {
                for (int i = 0; i < 15; ++i)  s1 += fsp[(n*15+i)*16 + k] * Rm[i*15 + j];
                for (int jj = 0; jj < 15; ++jj) s2 += dshp[(n*15+jj)*16 + k] * Im[j*15 + jj];
            }
            FRt[idx] = s1;
            DIt[idx] = s2;
        }
        __syncthreads();

        if (tid < 225) {
            int m = tid / 15, n = tid % 15;
            float acc = 0.0f;
            for (int j = 0; j < 15; ++j) {
                const float* fa = &fsp[(m*15+j)*16];
                const float* fb = &FRt[(n*15+j)*16];
                const float* fc = &DIt[(n*15+j)*16];
#pragma unroll
                for (int kk = 0; kk < 4; ++kk) {
                    float4 a4 = *(const float4*)(fa + 4*kk);
                    float4 b4 = *(const float4*)(fb + 4*kk);
                    float4 c4 = *(const float4*)(fc + 4*kk);
                    acc += a4.x*(b4.x + c4.x) + a4.y*(b4.y + c4.y)
                         + a4.z*(b4.z + c4.z) + a4.w*(b4.w + c4.w);
                }
            }
            accA[tid] = -8.0f * acc;
        }
        if (tid < 15) {
            int m = tid;
            float s = 0.0f;
            for (int i = 0; i < 15; ++i)
                for (int j = 0; j < 15; ++j)
                    s += fsp[(i*15+m)*16 + j] * Im[i*15 + j];
            colv[m] = 4.0f * s;
        }
        __syncthreads();

        float vg, vo;
        if (r == 0)      { vg = 0.0f;              vo = 0.0f; }
        else if (c == 0) { vg = colv[r-1];         vo = 0.0f; }
        else             { vg = accA[(r-1)*15 + (c-1)];
                           vo = -4.0f * fsp[(p*15 + (r-1))*16 + (c-1)]; }
        Lb16[c*512 + r*32 + p]      = (_Float16)vg;
        Lb16[c*512 + r*32 + 16 + p] = (_Float16)vo;
    } else {
        unsigned* lw = (unsigned*)sm;
        for (int idx = tid; idx < 200*36; idx += 256) lw[idx] = 0u;
        __syncthreads();
        for (int idx = tid; idx < 200*32; idx += 256) {
            int n = idx >> 5, tt = idx & 31;
            lw[n*36 + tt] = wt16[n*36 + tt];
        }
        __syncthreads();

        int q = tid & 3;
        int pp = tid >> 2;
        int sbase = (blockIdx.x - 16) * 256 + pp;

        float rc[4], rs[4], rc4[4], rs4[4];
#pragma unroll
        for (int i = 0; i < 4; ++i) {
            float d = 0.5f * PH_SCALE * t[sbase + 64*i];
            __sincosf((float)(q + 1) * d, &rs[i], &rc[i]);
            __sincosf(4.0f * d, &rs4[i], &rc4[i]);
        }

        float ga[4][15], oa[4][15];
#pragma unroll
        for (int i = 0; i < 4; ++i)
#pragma unroll
            for (int m = 0; m < 15; ++m) { ga[i][m] = 0.0f; oa[i][m] = 0.0f; }

#pragma unroll 1
        for (int k = 0; k < 50; ++k) {
            const uint4* rowv = (const uint4*)(lw + (4*k + q) * 36);
            unsigned us[32];
#pragma unroll
            for (int j = 0; j < 8; ++j) {
                uint4 a_ = rowv[j];
                us[4*j] = a_.x; us[4*j+1] = a_.y; us[4*j+2] = a_.z; us[4*j+3] = a_.w;
            }
#pragma unroll
            for (int i = 0; i < 4; ++i) {
                f16x2 cs = cvt_pk(rc[i], rs[i]);
#pragma unroll
                for (int m = 0; m < 15; ++m) {
                    ga[i][m] = dot2(cs, us[m],      ga[i][m]);
                    oa[i][m] = dot2(cs, us[16 + m], oa[i][m]);
                }
                float cn = rc[i]*rc4[i] - rs[i]*rs4[i];
                float sn = rs[i]*rc4[i] + rc[i]*rs4[i];
                rc[i] = cn; rs[i] = sn;
            }
        }

#pragma unroll
        for (int i = 0; i < 4; ++i)
#pragma unroll
            for (int m = 0; m < 15; ++m) {
                ga[i][m] += __shfl_xor(ga[i][m], 1, 64);
                ga[i][m] += __shfl_xor(ga[i][m], 2, 64);
                oa[i][m] += __shfl_xor(oa[i][m], 1, 64);
                oa[i][m] += __shfl_xor(oa[i][m], 2, 64);
            }

        float bgv[15], bov[15];
#pragma unroll
        for (int m = 0; m < 15; ++m) { bgv[m] = bg[m]; bov[m] = bo[m]; }

#pragma unroll
        for (int i = 0; i < 4; ++i) {
            float rv[32];
#pragma unroll
            for (int m = 0; m < 15; ++m) {
                float g = ga[i][m] + bgv[m];
                rv[m]      = g * g * INV_NORM;
                rv[16 + m] = (oa[i][m] + bov[m]) * INV_NORM;
            }
            rv[15] = 0.0f; rv[31] = 0.0f;
            unsigned u0  = packh(rv[0],  rv[1]),  u1  = packh(rv[2],  rv[3]);
            unsigned u2  = packh(rv[4],  rv[5]),  u3  = packh(rv[6],  rv[7]);
            unsigned u4  = packh(rv[8],  rv[9]),  u5  = packh(rv[10], rv[11]);
            unsigned u6  = packh(rv[12], rv[13]), u7  = packh(rv[14], rv[15]);
            unsigned u8  = packh(rv[16], rv[17]), u9  = packh(rv[18], rv[19]);
            unsigned u10 = packh(rv[20], rv[21]), u11 = packh(rv[22], rv[23]);
            unsigned u12 = packh(rv[24], rv[25]), u13 = packh(rv[26], rv[27]);
            unsigned u14 = packh(rv[28], rv[29]), u15 = packh(rv[30], rv[31]);
            uint4 wr;
            if      (q == 0) wr = make_uint4(u0,  u1,  u2,  u3);
            else if (q == 1) wr = make_uint4(u4,  u5,  u6,  u7);
            else if (q == 2) wr = make_uint4(u8,  u9,  u10, u11);
            else             wr = make_uint4(u12, u13, u14, u15);
            *(uint4*)(coef16 + (size_t)(sbase + 64*i) * 16 + 4*q) = wr;
        }
    }
}

__global__ __launch_bounds__(256) void k_main(const float* __restrict__ x,
                                              const unsigned* __restrict__ coef16,
                                              const _Float16* __restrict__ Lb16,
                                              float* __restrict__ out) {
    __shared__ float wl[4 * 16 * 20];
    int tid  = threadIdx.x;
    int wave = tid >> 6, lane = tid & 63;
    int grp  = lane >> 4, sl = lane & 15;
    int s    = blockIdx.x * 64 + wave * 16 + sl;

    f16x8 bh = *(const f16x8*)((const _Float16*)coef16 + (size_t)s * 32 + grp * 8);

    f32x4 acc[16];
    f32x4 zero4 = {0.0f, 0.0f, 0.0f, 0.0f};
#pragma unroll
    for (int c = 0; c < 16; ++c) {
        f16x8 af = *(const f16x8*)(Lb16 + c*512 + sl*32 + grp*8);
        acc[c] = __builtin_amdgcn_mfma_f32_16x16x32_f16(af, bh, zero4, 0, 0, 0);
    }

    float4 wv;
    if (grp == 0) {
        const float* xp = x + (size_t)s * 15;
        wv = make_float4(1.0f, xp[0], xp[1], xp[2]);
    } else {
        const float* xp = x + (size_t)s * 15 + 4*grp - 1;
        wv = make_float4(xp[0], xp[1], xp[2], xp[3]);
    }
    float4 accv = wv;

    float* slot = wl + wave*320 + sl*20;
#pragma unroll
    for (int k = 1; k <= KTAY; ++k) {
        *(float4*)(slot + 4*grp) = wv;
        float wz[16];
        {
            float4 a = *(const float4*)(slot + 0);
            wz[0]=a.x; wz[1]=a.y; wz[2]=a.z; wz[3]=a.w;
            float4 b = *(const float4*)(slot + 4);
            wz[4]=b.x; wz[5]=b.y; wz[6]=b.z; wz[7]=b.w;
            float4 c = *(const float4*)(slot + 8);
            wz[8]=c.x; wz[9]=c.y; wz[10]=c.z; wz[11]=c.w;
            float4 d = *(const float4*)(slot + 12);
            wz[12]=d.x; wz[13]=d.y; wz[14]=d.z; wz[15]=d.w;
        }
        float nx = 0.0f, ny = 0.0f, nz = 0.0f, nw = 0.0f;
#pragma unroll
        for (int c = 0; c < 16; ++c) {
            f32x4 A = acc[c];
            float wc = wz[c];
            nx += A.x * wc; ny += A.y * wc; nz += A.z * wc; nw += A.w * wc;
        }
        float sc = DTC / (float)k;
        wv = make_float4(nx*sc, ny*sc, nz*sc, nw*sc);
        accv.x += wv.x; accv.y += wv.y; accv.z += wv.z; accv.w += wv.w;
    }

    float* op = out + (size_t)s * 15 - 1;
    int row = 4 * grp;
    if (row > 0) op[row] = accv.x;
    op[row + 1] = accv.y;
    op[row + 2] = accv.z;
    op[row + 3] = accv.w;
}

// ---------------------------------------------------------------------------
extern "C" void kernel_launch(void* const* d_in, const int* in_sizes, int n_in,
                              void* d_out, int out_size, void* d_ws, size_t ws_size,
                              hipStream_t stream) {
    const float* t    = (const float*)d_in[0];
    const float* x    = (const float*)d_in[1];
    const float* u_re = (const float*)d_in[2];
    const float* u_im = (const float*)d_in[3];
    const float* ag   = (const float*)d_in[5];
    const float* wg   = (const float*)d_in[6];
    const float* bg   = (const float*)d_in[7];
    const float* ao   = (const float*)d_in[9];
    const float* wo   = (const float*)d_in[10];
    const float* bo   = (const float*)d_in[11];
    const float* f    = (const float*)d_in[12];
    const float* dten = (const float*)d_in[13];
    float* out = (float*)d_out;
    float* ws  = (float*)d_ws;

    float*    u_ws   = ws;                          // 512 floats
    _Float16* Lb16   = (_Float16*)(ws + 512);       // 8192 halves
    unsigned* wt16   = (unsigned*)(ws + 4608);      // 7200 uints
    unsigned* coef16 = (unsigned*)(ws + 12288);     // 65536*16 uints = 4 MB

    void* args[] = {
        (void*)&t, (void*)&x, (void*)&u_re, (void*)&u_im,
        (void*)&ag, (void*)&wg, (void*)&bg,
        (void*)&ao, (void*)&wo, (void*)&bo,
        (void*)&f, (void*)&dten,
        (void*)&Lb16, (void*)&coef16, (void*)&out
    };
    hipError_t err = hipLaunchCooperativeKernel((const void*)k_all,
                                                dim3(256), dim3(256),
                                                args, 31744, stream);
    if (err != hipSuccess) {
        // Fallback: proven 3-kernel pipeline (round 6).
        hipLaunchKernelGGL(k_pre,  dim3(201),  dim3(256), 0,     stream,
                           u_re, u_im, ag, wg, ao, wo, u_ws, wt16);
        hipLaunchKernelGGL(k_mid,  dim3(272),  dim3(256), 60480, stream,
                           f, dten, u_ws, t, bg, bo, wt16, Lb16, coef16);
        hipLaunchKernelGGL(k_main, dim3(1024), dim3(256), 0,     stream,
                           x, coef16, Lb16, out);
    }
}

// Round 10
// 160.922 us; speedup vs baseline: 1.3786x; 1.3786x over previous
//
#include <hip/hip_runtime.h>
#include <hip/hip_bf16.h>
#include <math.h>

// Problem constants
#define NB      65536
#define NFQ     199
#define DTC     0.05f
#define INV_NORM (1.0f/150.0f)
#define PH_SCALE 1.2566370614359172f   // 2*pi / T_PERIOD
#define KTAY    10                      // Taylor terms for expm(DT*L) action
#define KTAY_U  18                      // Taylor terms for u = expm(i*theta)

typedef _Float16 f16x8 __attribute__((ext_vector_type(8)));
typedef _Float16 f16x2 __attribute__((ext_vector_type(2)));
typedef float    f32x4 __attribute__((ext_vector_type(4)));

static __device__ __forceinline__ f16x2 u2h(unsigned u) {
    return __builtin_bit_cast(f16x2, u);
}
static __device__ __forceinline__ unsigned packh(float lo, float hi) {
    f16x2 h; h.x = (_Float16)lo; h.y = (_Float16)hi;
    return __builtin_bit_cast(unsigned, h);
}
static __device__ __forceinline__ f16x2 cvt_pk(float lo, float hi) {
    return __builtin_bit_cast(f16x2, __builtin_amdgcn_cvt_pkrtz(lo, hi));
}
// acc += cs . w  (f16 pair dot, f32 accumulate)
static __device__ __forceinline__ float dot2(f16x2 cs, unsigned wbits, float acc) {
#if __has_builtin(__builtin_amdgcn_fdot2)
    return __builtin_amdgcn_fdot2(cs, u2h(wbits), acc, false);
#else
    f16x2 w = u2h(wbits);
    return acc + (float)cs.x * (float)w.x + (float)cs.y * (float)w.y;
#endif
}

extern __shared__ float sm[];   // dynamic LDS (31744 B)

// ===========================================================================
// Kernel A, grid 528 x 256:
//  blocks 0..15  : basis (inline redundant u) -> Lb16[c*512 + r*32 + g]
//  blocks 16..527: coef, 128 samples each; 8-lane groups, 4 samples/thread,
//                  25 rotation iterations (rows n = 8k+q), inline f16 table.
// ===========================================================================
__global__ __launch_bounds__(256) void k_A(
        const float* __restrict__ t,
        const float* __restrict__ u_re,const float* __restrict__ u_im,
        const float* __restrict__ ag,  const float* __restrict__ wg,
        const float* __restrict__ bg,  const float* __restrict__ ao,
        const float* __restrict__ wo,  const float* __restrict__ bo,
        const float* __restrict__ f,   const float* __restrict__ dten,
        _Float16* __restrict__ Lb16,   unsigned* __restrict__ coef16) {
    int tid = threadIdx.x;
    int bid = blockIdx.x;

    if (bid < 16) {
        // ================= basis path (proven in round 8) =================
        if (bid == 15) {   // zero slices g=15, g=31
            int c = tid >> 4, r = tid & 15;
            Lb16[c*512 + r*32 + 15] = (_Float16)0.0f;
            Lb16[c*512 + r*32 + 31] = (_Float16)0.0f;
        } else {
            int p = bid;
            unsigned* fd16 = (unsigned*)sm;     // 3600 uints: (f,d) f16 pairs, [a][b][k] stride16
            float* S    = sm + 3600;            // 3600: FR+DI merged, [n][j][k] stride16
            float* Rm   = sm + 7200;            // 225
            float* Im   = sm + 7425;            // 225
            float* accA = sm + 7650;            // 225
            float* colv = sm + 7875;            // 15
            float* sur  = sm + 7890;            // 15
            float* sui  = sm + 7905;            // 15
            // u-compute scratch overlays the S region (done before S is written)
            float* Mre  = sm + 3600;            // 225
            float* Mim  = sm + 3825;            // 225
            float* creb = sm + 4050;            // 2 x 225
            float* cimb = sm + 4500;            // 2 x 225

            for (int idx = tid; idx < 3600; idx += 256) {
                int k = idx & 15, ab = idx >> 4;
                float fv = 0.0f, dv = 0.0f;
                if (k < 15) { fv = f[ab*15 + k]; dv = dten[ab*15 + k]; }
                fd16[idx] = packh(fv, dv);
            }
            // ---- u = expm(i*theta), skew-Hermitian Taylor (redundant/block) ----
            float accre = 0.0f, accim = 0.0f;
            if (tid < 225) {
                int a = tid / 15, b = tid % 15;
                float tre = u_re[a*15+b] + u_re[b*15+a];
                float tim = u_im[a*15+b] - u_im[b*15+a];
                Mre[tid] = -tim;
                Mim[tid] =  tre;
                float id = (a == b) ? 1.0f : 0.0f;
                creb[tid] = id; cimb[tid] = 0.0f;
                accre = id;
            }
            __syncthreads();
            int cur = 0;
            for (int k = 1; k <= KTAY_U; ++k) {
                float nre = 0.0f, nim = 0.0f;
                if (tid < 225) {
                    int a = tid / 15, b = tid % 15;
                    for (int j = 0; j < 15; ++j) {
                        float mre = Mre[a*15+j], mim = Mim[a*15+j];
                        float xre = creb[cur*225 + j*15+b], xim = cimb[cur*225 + j*15+b];
                        nre += mre*xre - mim*xim;
                        nim += mre*xim + mim*xre;
                    }
                    float inv = 1.0f / (float)k;
                    nre *= inv; nim *= inv;
                    creb[(cur^1)*225 + tid] = nre; cimb[(cur^1)*225 + tid] = nim;
                    accre += nre; accim += nim;
                }
                __syncthreads();
                cur ^= 1;
            }
            // column p of u
            if (tid < 225 && (tid % 15) == p) { sur[tid/15] = accre; sui[tid/15] = accim; }
            __syncthreads();
            if (tid < 225) {
                int i = tid / 15, j = tid % 15;
                Rm[tid] = sur[i]*sur[j] + sui[i]*sui[j];   // Re(u_ip conj(u_jp))
                Im[tid] = sui[i]*sur[j] - sur[i]*sui[j];   // Im(u_ip conj(u_jp))
            }
            __syncthreads();
            // S[n][j][k] = sum_i f[n,i,k]*Rm[i,j] + sum_i d[n,i,k]*Im[j,i]
            for (int idx = tid; idx < 3600; idx += 256) {
                int k  = idx & 15;
                int nj = idx >> 4;
                int n  = nj / 15;
                int j  = nj % 15;
                float s1 = 0.0f, s2 = 0.0f;
                if (k < 15) {
                    for (int i = 0; i < 15; ++i) {
                        f16x2 fd = u2h(fd16[(n*15+i)*16 + k]);
                        s1 += (float)fd.x * Rm[i*15 + j];
                        s2 += (float)fd.y * Im[j*15 + i];
                    }
                }
                S[idx] = s1 + s2;
            }
            __syncthreads();
            if (tid < 225) {
                int m = tid / 15, n = tid % 15;
                float acc = 0.0f;
                for (int j = 0; j < 15; ++j) {
                    const unsigned* fa = &fd16[(m*15+j)*16];
                    const float*    fs = &S   [(n*15+j)*16];
                    for (int k = 0; k < 15; ++k) {
                        f16x2 fd = u2h(fa[k]);
                        acc += (float)fd.x * fs[k];
                    }
                }
                accA[tid] = -8.0f * acc;
            }
            if (tid < 15) {
                int m = tid;
                float s = 0.0f;
                for (int i = 0; i < 15; ++i)
                    for (int j = 0; j < 15; ++j) {
                        f16x2 fd = u2h(fd16[(i*15+m)*16 + j]);
                        s += (float)fd.x * Im[i*15 + j];
                    }
                colv[m] = 4.0f * s;
            }
            __syncthreads();
            {
                int c = tid >> 4, r = tid & 15;
                float vg, vo;
                if (r == 0)      { vg = 0.0f;              vo = 0.0f; }
                else if (c == 0) { vg = colv[r-1];         vo = 0.0f; }
                else             { vg = accA[(r-1)*15 + (c-1)];
                                   f16x2 fd = u2h(fd16[(p*15 + (r-1))*16 + (c-1)]);
                                   vo = -4.0f * (float)fd.x; }
                Lb16[c*512 + r*32 + p]      = (_Float16)vg;
                Lb16[c*512 + r*32 + 16 + p] = (_Float16)vo;
            }
        }
    } else {
        // ================= coef path (blocks 16..527, 128 samples each) =====
        unsigned* lw = (unsigned*)sm;       // 200 rows x 36 uints (28.8 KB)
        for (int idx = tid; idx < 200*36; idx += 256) lw[idx] = 0u;
        __syncthreads();
        // build f16 (cos,sin) weight table inline; lanes sweep n -> coalesced
        for (int idx = tid; idx < 15*200; idx += 256) {
            int m = idx / 200, n = idx % 200;
            if (n < NFQ)
                lw[n*36 + m] = packh(wg[m*398 + n]       * ag[n],
                                     wg[m*398 + 199 + n] * ag[199 + n]);
        }
        for (int idx = tid; idx < 15*200; idx += 256) {
            int m = idx / 200, n = idx % 200;
            if (n < NFQ)
                lw[n*36 + 16 + m] = packh(wo[m*398 + n]       * ao[n],
                                          wo[m*398 + 199 + n] * ao[199 + n]);
        }
        __syncthreads();

        int q  = tid & 7;         // 8-lane group: freq rows n = 8k+q, k=0..24
        int pp = tid >> 3;        // 0..31
        int sbase = (bid - 16) * 128 + pp;   // + 32*i, i=0..3

        float rc[4], rs[4], rc8[4], rs8[4];
#pragma unroll
        for (int i = 0; i < 4; ++i) {
            float d = 0.5f * PH_SCALE * t[sbase + 32*i];
            __sincosf((float)(q + 1) * d, &rs[i], &rc[i]);
            __sincosf(8.0f * d, &rs8[i], &rc8[i]);
        }

        float ga[4][15], oa[4][15];
#pragma unroll
        for (int i = 0; i < 4; ++i)
#pragma unroll
            for (int m = 0; m < 15; ++m) { ga[i][m] = 0.0f; oa[i][m] = 0.0f; }

#pragma unroll 1
        for (int k = 0; k < 25; ++k) {
            const uint4* rowv = (const uint4*)(lw + (8*k + q) * 36);
            unsigned us[32];
#pragma unroll
            for (int j = 0; j < 8; ++j) {
                uint4 a_ = rowv[j];
                us[4*j] = a_.x; us[4*j+1] = a_.y; us[4*j+2] = a_.z; us[4*j+3] = a_.w;
            }
#pragma unroll
            for (int i = 0; i < 4; ++i) {
                f16x2 cs = cvt_pk(rc[i], rs[i]);
#pragma unroll
                for (int m = 0; m < 15; ++m) {
                    ga[i][m] = dot2(cs, us[m],      ga[i][m]);
                    oa[i][m] = dot2(cs, us[16 + m], oa[i][m]);
                }
                float cn = rc[i]*rc8[i] - rs[i]*rs8[i];
                float sn = rs[i]*rc8[i] + rc[i]*rs8[i];
                rc[i] = cn; rs[i] = sn;
            }
        }

        // reduce across the 8-lane group
#pragma unroll
        for (int i = 0; i < 4; ++i)
#pragma unroll
            for (int m = 0; m < 15; ++m) {
                ga[i][m] += __shfl_xor(ga[i][m], 1, 64);
                ga[i][m] += __shfl_xor(ga[i][m], 2, 64);
                ga[i][m] += __shfl_xor(ga[i][m], 4, 64);
                oa[i][m] += __shfl_xor(oa[i][m], 1, 64);
                oa[i][m] += __shfl_xor(oa[i][m], 2, 64);
                oa[i][m] += __shfl_xor(oa[i][m], 4, 64);
            }

        float bgv[15], bov[15];
#pragma unroll
        for (int m = 0; m < 15; ++m) { bgv[m] = bg[m]; bov[m] = bo[m]; }

        // Only lanes q<4 write: record is 16 uints; lane q covers rv[8q..8q+7].
        // (Round-9 bug: q up to 7 read rv OOB and clobbered the next record.)
#pragma unroll
        for (int i = 0; i < 4; ++i) {
            float rv[32];
#pragma unroll
            for (int m = 0; m < 15; ++m) {
                float g = ga[i][m] + bgv[m];
                rv[m]      = g * g * INV_NORM;
                rv[16 + m] = (oa[i][m] + bov[m]) * INV_NORM;
            }
            rv[15] = 0.0f; rv[31] = 0.0f;
            if (q < 4) {
                uint4 wr = make_uint4(packh(rv[8*q+0], rv[8*q+1]),
                                      packh(rv[8*q+2], rv[8*q+3]),
                                      packh(rv[8*q+4], rv[8*q+5]),
                                      packh(rv[8*q+6], rv[8*q+7]));
                *(uint4*)(coef16 + (size_t)(sbase + 32*i) * 16 + 4*q) = wr;
            }
        }
    }
}

// ===========================================================================
// Kernel B: main (round-6 proven). One wave = 16 samples.
//  16x mfma_f32_16x16x32_f16, D-layout col=lane&15=sample, row=(lane>>4)*4+i.
//  Taylor w-exchange: wave-private LDS, stride-20 rows. No barriers.
// ===========================================================================
__global__ __launch_bounds__(256) void k_main(const float* __restrict__ x,
                                              const unsigned* __restrict__ coef16,
                                              const _Float16* __restrict__ Lb16,
                                              float* __restrict__ out) {
    __shared__ float wl[4 * 16 * 20];
    int tid  = threadIdx.x;
    int wave = tid >> 6, lane = tid & 63;
    int grp  = lane >> 4, sl = lane & 15;
    int s    = blockIdx.x * 64 + wave * 16 + sl;

    f16x8 bh = *(const f16x8*)((const _Float16*)coef16 + (size_t)s * 32 + grp * 8);

    f32x4 acc[16];
    f32x4 zero4 = {0.0f, 0.0f, 0.0f, 0.0f};
#pragma unroll
    for (int c = 0; c < 16; ++c) {
        f16x8 af = *(const f16x8*)(Lb16 + c*512 + sl*32 + grp*8);
        acc[c] = __builtin_amdgcn_mfma_f32_16x16x32_f16(af, bh, zero4, 0, 0, 0);
    }

    float4 wv;
    if (grp == 0) {
        const float* xp = x + (size_t)s * 15;
        wv = make_float4(1.0f, xp[0], xp[1], xp[2]);
    } else {
        const float* xp = x + (size_t)s * 15 + 4*grp - 1;
        wv = make_float4(xp[0], xp[1], xp[2], xp[3]);
    }
    float4 accv = wv;

    float* slot = wl + wave*320 + sl*20;
#pragma unroll
    for (int k = 1; k <= KTAY; ++k) {
        *(float4*)(slot + 4*grp) = wv;      // wave-synchronous, in-order DS
        float wz[16];
        {
            float4 a = *(const float4*)(slot + 0);
            wz[0]=a.x; wz[1]=a.y; wz[2]=a.z; wz[3]=a.w;
            float4 b = *(const float4*)(slot + 4);
            wz[4]=b.x; wz[5]=b.y; wz[6]=b.z; wz[7]=b.w;
            float4 c = *(const float4*)(slot + 8);
            wz[8]=c.x; wz[9]=c.y; wz[10]=c.z; wz[11]=c.w;
            float4 d = *(const float4*)(slot + 12);
            wz[12]=d.x; wz[13]=d.y; wz[14]=d.z; wz[15]=d.w;
        }
        float nx = 0.0f, ny = 0.0f, nz = 0.0f, nw = 0.0f;
#pragma unroll
        for (int c = 0; c < 16; ++c) {
            f32x4 A = acc[c];
            float wc = wz[c];
            nx += A.x * wc; ny += A.y * wc; nz += A.z * wc; nw += A.w * wc;
        }
        float sc = DTC / (float)k;
        wv = make_float4(nx*sc, ny*sc, nz*sc, nw*sc);
        accv.x += wv.x; accv.y += wv.y; accv.z += wv.z; accv.w += wv.w;
    }

    float* op = out + (size_t)s * 15 - 1;
    int row = 4 * grp;
    if (row > 0) op[row] = accv.x;
    op[row + 1] = accv.y;
    op[row + 2] = accv.z;
    op[row + 3] = accv.w;
}

// ---------------------------------------------------------------------------
extern "C" void kernel_launch(void* const* d_in, const int* in_sizes, int n_in,
                              void* d_out, int out_size, void* d_ws, size_t ws_size,
                              hipStream_t stream) {
    const float* t    = (const float*)d_in[0];
    const float* x    = (const float*)d_in[1];
    const float* u_re = (const float*)d_in[2];
    const float* u_im = (const float*)d_in[3];
    const float* ag   = (const float*)d_in[5];
    const float* wg   = (const float*)d_in[6];
    const float* bg   = (const float*)d_in[7];
    const float* ao   = (const float*)d_in[9];
    const float* wo   = (const float*)d_in[10];
    const float* bo   = (const float*)d_in[11];
    const float* f    = (const float*)d_in[12];
    const float* dten = (const float*)d_in[13];
    float* out = (float*)d_out;

    _Float16* Lb16   = (_Float16*)d_ws;                       // 8192 halves = 16 KB
    unsigned* coef16 = (unsigned*)((char*)d_ws + 16384);      // 65536*16 uints = 4 MB

    hipLaunchKernelGGL(k_A,    dim3(528),  dim3(256), 31744, stream,
                       t, u_re, u_im, ag, wg, bg, ao, wo, bo, f, dten,
                       Lb16, coef16);
    hipLaunchKernelGGL(k_main, dim3(1024), dim3(256), 0,     stream,
                       x, coef16, Lb16, out);
}

// Round 11
// 157.515 us; speedup vs baseline: 1.4084x; 1.0216x over previous
//
#include <hip/hip_runtime.h>
#include <hip/hip_bf16.h>
#include <math.h>

// Problem constants
#define NB      65536
#define NFQ     199
#define DTC     0.05f
#define INV_NORM (1.0f/150.0f)
#define PH_SCALE 1.2566370614359172f   // 2*pi / T_PERIOD
#define KTAY    10                      // Taylor terms for expm(DT*L) action
#define KTAY_U  18                      // Taylor terms for u = expm(i*theta)

typedef _Float16 f16x8 __attribute__((ext_vector_type(8)));
typedef _Float16 f16x2 __attribute__((ext_vector_type(2)));
typedef float    f32x4 __attribute__((ext_vector_type(4)));

static __device__ __forceinline__ f16x2 u2h(unsigned u) {
    return __builtin_bit_cast(f16x2, u);
}
static __device__ __forceinline__ unsigned packh(float lo, float hi) {
    f16x2 h; h.x = (_Float16)lo; h.y = (_Float16)hi;
    return __builtin_bit_cast(unsigned, h);
}
static __device__ __forceinline__ f16x2 cvt_pk(float lo, float hi) {
    return __builtin_bit_cast(f16x2, __builtin_amdgcn_cvt_pkrtz(lo, hi));
}
// acc += cs . w  (f16 pair dot, f32 accumulate)
static __device__ __forceinline__ float dot2(f16x2 cs, unsigned wbits, float acc) {
#if __has_builtin(__builtin_amdgcn_fdot2)
    return __builtin_amdgcn_fdot2(cs, u2h(wbits), acc, false);
#else
    f16x2 w = u2h(wbits);
    return acc + (float)cs.x * (float)w.x + (float)cs.y * (float)w.y;
#endif
}

extern __shared__ float sm[];   // dynamic LDS

// ===========================================================================
// Kernel 1: k_pre (round-6 proven). Block 0: u = expm(i*theta) (18 Taylor
// terms, skew-Hermitian). Blocks 1..200: f16 weight table wt16[n][36].
// ===========================================================================
__global__ __launch_bounds__(256) void k_pre(const float* __restrict__ u_re,
                                             const float* __restrict__ u_im,
                                             const float* __restrict__ ag,
                                             const float* __restrict__ wg,
                                             const float* __restrict__ ao,
                                             const float* __restrict__ wo,
                                             float* __restrict__ ws_u,
                                             unsigned* __restrict__ wt16) {
    int tid = threadIdx.x;
    if (blockIdx.x == 0) {
        __shared__ float Mre[225], Mim[225];
        __shared__ float cre[2][225], cim[2][225];
        float accre = 0.0f, accim = 0.0f;
        if (tid < 225) {
            int a = tid / 15, b = tid % 15;
            float tre = u_re[a*15+b] + u_re[b*15+a];
            float tim = u_im[a*15+b] - u_im[b*15+a];
            Mre[tid] = -tim;
            Mim[tid] =  tre;
            float id = (a == b) ? 1.0f : 0.0f;
            cre[0][tid] = id; cim[0][tid] = 0.0f;
            accre = id;
        }
        __syncthreads();
        int cur = 0;
        for (int k = 1; k <= KTAY_U; ++k) {
            float nre = 0.0f, nim = 0.0f;
            if (tid < 225) {
                int a = tid / 15, b = tid % 15;
                for (int j = 0; j < 15; ++j) {
                    float mre = Mre[a*15+j], mim = Mim[a*15+j];
                    float xre = cre[cur][j*15+b], xim = cim[cur][j*15+b];
                    nre += mre*xre - mim*xim;
                    nim += mre*xim + mim*xre;
                }
                float inv = 1.0f / (float)k;
                nre *= inv; nim *= inv;
                cre[cur^1][tid] = nre; cim[cur^1][tid] = nim;
                accre += nre; accim += nim;
            }
            __syncthreads();
            cur ^= 1;
        }
        if (tid < 225) {
            ws_u[2*tid]   = accre;
            ws_u[2*tid+1] = accim;
        }
    } else {
        int n = blockIdx.x - 1;
        if (tid < 32) {
            unsigned v = 0u;
            if (n < NFQ) {
                if (tid < 15) {
                    v = packh(wg[tid*398 + n] * ag[n],
                              wg[tid*398 + 199 + n] * ag[199 + n]);
                } else if (tid >= 16 && tid < 31) {
                    int m = tid - 16;
                    v = packh(wo[m*398 + n] * ao[n],
                              wo[m*398 + 199 + n] * ao[199 + n]);
                }
            }
            wt16[n*36 + tid] = v;
        }
    }
}

// ===========================================================================
// Kernel 2: k_mid, grid 528 x 256, dynamic LDS 60480 B.
//  blocks 0..15  : basis (round-6 proven f32 path, reads ws_u) -> Lb16
//  blocks 16..527: coef, 128 samples each; 8-lane groups, 4 samples/thread,
//                  25 rotation iterations, table from global wt16.
// ===========================================================================
__global__ __launch_bounds__(256) void k_mid(const float* __restrict__ f,
                                             const float* __restrict__ dten,
                                             const float* __restrict__ ws_u,
                                             const float* __restrict__ t,
                                             const float* __restrict__ bg,
                                             const float* __restrict__ bo,
                                             const unsigned* __restrict__ wt16,
                                             _Float16* __restrict__ Lb16,
                                             unsigned* __restrict__ coef16) {
    int tid = threadIdx.x;
    if (blockIdx.x < 16) {
        // ================= basis path (round-6 proven) =================
        int p = blockIdx.x;
        int c = tid >> 4, r = tid & 15;
        if (p == 15) {
            Lb16[c*512 + r*32 + 15] = (_Float16)0.0f;
            Lb16[c*512 + r*32 + 31] = (_Float16)0.0f;
            return;
        }
        float* fsp  = sm;            // 3600  [a][b][k] stride16
        float* dshp = sm + 3600;     // 3600
        float* FRt  = sm + 7200;     // 3600  [n][j][k] stride16
        float* DIt  = sm + 10800;    // 3600
        float* Rm   = sm + 14400;    // 225
        float* Im   = sm + 14625;    // 225
        float* accA = sm + 14850;    // 225
        float* colv = sm + 15075;    // 15
        float* sur  = sm + 15090;    // 15
        float* sui  = sm + 15105;    // 15

        for (int idx = tid; idx < 3600; idx += 256) {
            int k = idx & 15, ab = idx >> 4;
            float fv = 0.0f, dv = 0.0f;
            if (k < 15) { fv = f[ab*15 + k]; dv = dten[ab*15 + k]; }
            fsp[idx] = fv; dshp[idx] = dv;
        }
        if (tid < 15) {
            sur[tid] = ws_u[2*(tid*15 + p)];
            sui[tid] = ws_u[2*(tid*15 + p) + 1];
        }
        __syncthreads();

        if (tid < 225) {
            int i = tid / 15, j = tid % 15;
            Rm[tid] = sur[i]*sur[j] + sui[i]*sui[j];
            Im[tid] = sui[i]*sur[j] - sur[i]*sui[j];
        }
        __syncthreads();

        for (int idx = tid; idx < 3600; idx += 256) {
            int k  = idx & 15;
            int nj = idx >> 4;
            int n  = nj / 15;
            int j  = nj % 15;
            float s1 = 0.0f, s2 = 0.0f;
            if (k < 15) {
                for (int i = 0; i < 15; ++i)  s1 += fsp[(n*15+i)*16 + k] * Rm[i*15 + j];
                for (int jj = 0; jj < 15; ++jj) s2 += dshp[(n*15+jj)*16 + k] * Im[j*15 + jj];
            }
            FRt[idx] = s1;
            DIt[idx] = s2;
        }
        __syncthreads();

        if (tid < 225) {
            int m = tid / 15, n = tid % 15;
            float acc = 0.0f;
            for (int j = 0; j < 15; ++j) {
                const float* fa = &fsp[(m*15+j)*16];
                const float* fb = &FRt[(n*15+j)*16];
                const float* fc = &DIt[(n*15+j)*16];
#pragma unroll
                for (int kk = 0; kk < 4; ++kk) {
                    float4 a4 = *(const float4*)(fa + 4*kk);
                    float4 b4 = *(const float4*)(fb + 4*kk);
                    float4 c4 = *(const float4*)(fc + 4*kk);
                    acc += a4.x*(b4.x + c4.x) + a4.y*(b4.y + c4.y)
                         + a4.z*(b4.z + c4.z) + a4.w*(b4.w + c4.w);
                }
            }
            accA[tid] = -8.0f * acc;
        }
        if (tid < 15) {
            int m = tid;
            float s = 0.0f;
            for (int i = 0; i < 15; ++i)
                for (int j = 0; j < 15; ++j)
                    s += fsp[(i*15+m)*16 + j] * Im[i*15 + j];
            colv[m] = 4.0f * s;
        }
        __syncthreads();

        float vg, vo;
        if (r == 0)      { vg = 0.0f;              vo = 0.0f; }
        else if (c == 0) { vg = colv[r-1];         vo = 0.0f; }
        else             { vg = accA[(r-1)*15 + (c-1)];
                           vo = -4.0f * fsp[(p*15 + (r-1))*16 + (c-1)]; }
        Lb16[c*512 + r*32 + p]      = (_Float16)vg;
        Lb16[c*512 + r*32 + 16 + p] = (_Float16)vo;
    } else {
        // ================= coef path (blocks 16..527, 128 samples) =========
        unsigned* lw = (unsigned*)sm;       // 200 rows x 36 uints (28.8 KB)
        for (int idx = tid; idx < 200*32; idx += 256) {
            int n = idx >> 5, tt = idx & 31;
            lw[n*36 + tt] = wt16[n*36 + tt];
        }
        __syncthreads();

        int q  = tid & 7;         // 8-lane group: freq rows n = 8k+q, k=0..24
        int pp = tid >> 3;        // 0..31
        int sbase = (blockIdx.x - 16) * 128 + pp;   // + 32*i, i=0..3

        float rc[4], rs[4], rc8[4], rs8[4];
#pragma unroll
        for (int i = 0; i < 4; ++i) {
            float d = 0.5f * PH_SCALE * t[sbase + 32*i];
            __sincosf((float)(q + 1) * d, &rs[i], &rc[i]);
            __sincosf(8.0f * d, &rs8[i], &rc8[i]);
        }

        float ga[4][15], oa[4][15];
#pragma unroll
        for (int i = 0; i < 4; ++i)
#pragma unroll
            for (int m = 0; m < 15; ++m) { ga[i][m] = 0.0f; oa[i][m] = 0.0f; }

#pragma unroll 1
        for (int k = 0; k < 25; ++k) {
            const uint4* rowv = (const uint4*)(lw + (8*k + q) * 36);
            unsigned us[32];
#pragma unroll
            for (int j = 0; j < 8; ++j) {
                uint4 a_ = rowv[j];
                us[4*j] = a_.x; us[4*j+1] = a_.y; us[4*j+2] = a_.z; us[4*j+3] = a_.w;
            }
#pragma unroll
            for (int i = 0; i < 4; ++i) {
                f16x2 cs = cvt_pk(rc[i], rs[i]);
#pragma unroll
                for (int m = 0; m < 15; ++m) {
                    ga[i][m] = dot2(cs, us[m],      ga[i][m]);
                    oa[i][m] = dot2(cs, us[16 + m], oa[i][m]);
                }
                float cn = rc[i]*rc8[i] - rs[i]*rs8[i];
                float sn = rs[i]*rc8[i] + rc[i]*rs8[i];
                rc[i] = cn; rs[i] = sn;
            }
        }

        // reduce across the 8-lane group
#pragma unroll
        for (int i = 0; i < 4; ++i)
#pragma unroll
            for (int m = 0; m < 15; ++m) {
                ga[i][m] += __shfl_xor(ga[i][m], 1, 64);
                ga[i][m] += __shfl_xor(ga[i][m], 2, 64);
                ga[i][m] += __shfl_xor(ga[i][m], 4, 64);
                oa[i][m] += __shfl_xor(oa[i][m], 1, 64);
                oa[i][m] += __shfl_xor(oa[i][m], 2, 64);
                oa[i][m] += __shfl_xor(oa[i][m], 4, 64);
            }

        float bgv[15], bov[15];
#pragma unroll
        for (int m = 0; m < 15; ++m) { bgv[m] = bg[m]; bov[m] = bo[m]; }

        // record = 16 uints; lane q<4 covers rv[8q..8q+7] (round-9 OOB fixed)
#pragma unroll
        for (int i = 0; i < 4; ++i) {
            float rv[32];
#pragma unroll
            for (int m = 0; m < 15; ++m) {
                float g = ga[i][m] + bgv[m];
                rv[m]      = g * g * INV_NORM;
                rv[16 + m] = (oa[i][m] + bov[m]) * INV_NORM;
            }
            rv[15] = 0.0f; rv[31] = 0.0f;
            if (q < 4) {
                uint4 wr = make_uint4(packh(rv[8*q+0], rv[8*q+1]),
                                      packh(rv[8*q+2], rv[8*q+3]),
                                      packh(rv[8*q+4], rv[8*q+5]),
                                      packh(rv[8*q+6], rv[8*q+7]));
                *(uint4*)(coef16 + (size_t)(sbase + 32*i) * 16 + 4*q) = wr;
            }
        }
    }
}

// ===========================================================================
// Kernel 3: k_main (proven). One wave = 16 samples.
//  16x mfma_f32_16x16x32_f16, D-layout col=lane&15=sample, row=(lane>>4)*4+i.
//  Taylor w-exchange: wave-private LDS, stride-20 rows. No barriers.
// ===========================================================================
__global__ __launch_bounds__(256) void k_main(const float* __restrict__ x,
                                              const unsigned* __restrict__ coef16,
                                              const _Float16* __restrict__ Lb16,
                                              float* __restrict__ out) {
    __shared__ float wl[4 * 16 * 20];
    int tid  = threadIdx.x;
    int wave = tid >> 6, lane = tid & 63;
    int grp  = lane >> 4, sl = lane & 15;
    int s    = blockIdx.x * 64 + wave * 16 + sl;

    f16x8 bh = *(const f16x8*)((const _Float16*)coef16 + (size_t)s * 32 + grp * 8);

    f32x4 acc[16];
    f32x4 zero4 = {0.0f, 0.0f, 0.0f, 0.0f};
#pragma unroll
    for (int c = 0; c < 16; ++c) {
        f16x8 af = *(const f16x8*)(Lb16 + c*512 + sl*32 + grp*8);
        acc[c] = __builtin_amdgcn_mfma_f32_16x16x32_f16(af, bh, zero4, 0, 0, 0);
    }

    float4 wv;
    if (grp == 0) {
        const float* xp = x + (size_t)s * 15;
        wv = make_float4(1.0f, xp[0], xp[1], xp[2]);
    } else {
        const float* xp = x + (size_t)s * 15 + 4*grp - 1;
        wv = make_float4(xp[0], xp[1], xp[2], xp[3]);
    }
    float4 accv = wv;

    float* slot = wl + wave*320 + sl*20;
#pragma unroll
    for (int k = 1; k <= KTAY; ++k) {
        *(float4*)(slot + 4*grp) = wv;      // wave-synchronous, in-order DS
        float wz[16];
        {
            float4 a = *(const float4*)(slot + 0);
            wz[0]=a.x; wz[1]=a.y; wz[2]=a.z; wz[3]=a.w;
            float4 b = *(const float4*)(slot + 4);
            wz[4]=b.x; wz[5]=b.y; wz[6]=b.z; wz[7]=b.w;
            float4 c = *(const float4*)(slot + 8);
            wz[8]=c.x; wz[9]=c.y; wz[10]=c.z; wz[11]=c.w;
            float4 d = *(const float4*)(slot + 12);
            wz[12]=d.x; wz[13]=d.y; wz[14]=d.z; wz[15]=d.w;
        }
        float nx = 0.0f, ny = 0.0f, nz = 0.0f, nw = 0.0f;
#pragma unroll
        for (int c = 0; c < 16; ++c) {
            f32x4 A = acc[c];
            float wc = wz[c];
            nx += A.x * wc; ny += A.y * wc; nz += A.z * wc; nw += A.w * wc;
        }
        float sc = DTC / (float)k;
        wv = make_float4(nx*sc, ny*sc, nz*sc, nw*sc);
        accv.x += wv.x; accv.y += wv.y; accv.z += wv.z; accv.w += wv.w;
    }

    float* op = out + (size_t)s * 15 - 1;
    int row = 4 * grp;
    if (row > 0) op[row] = accv.x;
    op[row + 1] = accv.y;
    op[row + 2] = accv.z;
    op[row + 3] = accv.w;
}

// ---------------------------------------------------------------------------
extern "C" void kernel_launch(void* const* d_in, const int* in_sizes, int n_in,
                              void* d_out, int out_size, void* d_ws, size_t ws_size,
                              hipStream_t stream) {
    const float* t    = (const float*)d_in[0];
    const float* x    = (const float*)d_in[1];
    const float* u_re = (const float*)d_in[2];
    const float* u_im = (const float*)d_in[3];
    const float* ag   = (const float*)d_in[5];
    const float* wg   = (const float*)d_in[6];
    const float* bg   = (const float*)d_in[7];
    const float* ao   = (const float*)d_in[9];
    const float* wo   = (const float*)d_in[10];
    const float* bo   = (const float*)d_in[11];
    const float* f    = (const float*)d_in[12];
    const float* dten = (const float*)d_in[13];
    float* out = (float*)d_out;
    float* ws  = (float*)d_ws;

    float*    u_ws   = ws;                          // 512 floats
    _Float16* Lb16   = (_Float16*)(ws + 512);       // 8192 halves
    unsigned* wt16   = (unsigned*)(ws + 4608);      // 7200 uints
    unsigned* coef16 = (unsigned*)(ws + 12288);     // 65536*16 uints = 4 MB

    hipLaunchKernelGGL(k_pre,  dim3(201),  dim3(256), 0,     stream,
                       u_re, u_im, ag, wg, ao, wo, u_ws, wt16);
    hipLaunchKernelGGL(k_mid,  dim3(528),  dim3(256), 60480, stream,
                       f, dten, u_ws, t, bg, bo, wt16, Lb16, coef16);
    hipLaunchKernelGGL(k_main, dim3(1024), dim3(256), 0,     stream,
                       x, coef16, Lb16, out);
}